// Round 4
// baseline (18579.524 us; speedup 1.0000x reference)
//
#include <hip/hip_runtime.h>
#include <hip/hip_bf16.h>

typedef __bf16 bf16x8 __attribute__((ext_vector_type(8)));
typedef float f32x4 __attribute__((ext_vector_type(4)));

#define B_ 128
#define S_ 1024
#define E_ 512
#define H_ 512
#define TOK 32            // tokens (sequences) per group
#define KROWS 64          // gate-rows per wg: 2 cells x 4 gates x 8 columns
#define WSTRIDE 1032      // 1024 + 8 bf16 pad (row stride 516 dwords == 4 mod 32)
#define GSTR 65           // gbuf row stride (f32)
#define NGRP 4
#define WPG 64            // workgroups per group
#define FSTR 16           // flag stride in dwords (64B padding, one wg per line-half)
#define SMEM_BYTES (KROWS * WSTRIDE * 2 + 64 * 4 + TOK * GSTR * 4)  // 140672

__device__ __forceinline__ float sigf(float x) { return 1.0f / (1.0f + __expf(-x)); }

__device__ __forceinline__ bf16x8 cvt8(float4 a, float4 b) {
    bf16x8 r;
    r[0] = (__bf16)a.x; r[1] = (__bf16)a.y; r[2] = (__bf16)a.z; r[3] = (__bf16)a.w;
    r[4] = (__bf16)b.x; r[5] = (__bf16)b.y; r[6] = (__bf16)b.z; r[7] = (__bf16)b.w;
    return r;
}

__global__ void init_ws_kernel(unsigned int* bar) {
    // zero the whole flag region: NGRP * WPG * FSTR dwords = 16 KB
    for (int i = threadIdx.x; i < NGRP * WPG * FSTR; i += 256) bar[i] = 0u;
}

__global__ void __launch_bounds__(512, 2)
lstm_kernel(const int* __restrict__ inp, const float* __restrict__ embed,
            const float* __restrict__ Wih, const float* __restrict__ Whh,
            const float* __restrict__ bih, const float* __restrict__ bhh,
            float* __restrict__ out, unsigned int* __restrict__ bar,
            __hip_bfloat16* __restrict__ hbuf)
{
    extern __shared__ char smem[];
    __hip_bfloat16* wbuf = (__hip_bfloat16*)smem;                 // [KROWS][WSTRIDE], [0,512)=W_ih row, [512,1024)=W_hh row
    float* bias_l = (float*)(smem + KROWS * WSTRIDE * 2);         // [64]
    float* gbuf   = bias_l + 64;                                  // [TOK][GSTR]

    const int tid = threadIdx.x;
    const int bid = blockIdx.x;
    const int grp = bid & 3;       // group: 64 wgs on XCDs {grp, grp+4}
    const int r   = bid >> 2;      // 0..63 column-block
    const int j0  = r * 8;

    // ---- stage weights (f32 -> bf16) into LDS, once. row n = cell*32 + gate*8 + jj ----
    for (int it = tid; it < KROWS * 256; it += 512) {
        int n = it >> 8;
        int q = it & 255;          // float4 index: 0..127 -> W_ih, 128..255 -> W_hh
        int cell = n >> 5, rem = n & 31, gate = rem >> 3, jj = rem & 7;
        size_t grow = (size_t)(cell * 2048 + gate * 512 + j0 + jj);
        float4 v;
        int dstoff;
        if (q < 128) { v = ((const float4*)(Wih + grow * E_))[q];       dstoff = q * 4; }
        else         { v = ((const float4*)(Whh + grow * H_))[q - 128]; dstoff = 512 + (q - 128) * 4; }
        __hip_bfloat16* dst = wbuf + n * WSTRIDE + dstoff;
        dst[0] = __float2bfloat16(v.x); dst[1] = __float2bfloat16(v.y);
        dst[2] = __float2bfloat16(v.z); dst[3] = __float2bfloat16(v.w);
    }
    if (tid < 64) {
        int n = tid, cell = n >> 5, rem = n & 31, gate = rem >> 3, jj = rem & 7;
        size_t off = (size_t)cell * 2048 + gate * 512 + j0 + jj;
        bias_l[tid] = bih[off] + bhh[off];
    }
    __syncthreads();

    // ---- MFMA task mapping: 8 waves = 2 token-tiles x 4 row-tiles ----
    const int lane = tid & 63, wid = tid >> 6;
    const int lm = lane & 15, quad = lane >> 4;
    const int mtile = wid & 1, rho = wid >> 1;
    const int tokA = grp * TOK + mtile * 16 + lm;             // A-operand token (m = lm)
    const float* xbase = embed + (size_t)tokA * S_ * E_ + quad * 8;
    const __hip_bfloat16* wx = wbuf + (rho * 16 + lm) * WSTRIDE + quad * 8;
    const __hip_bfloat16* wh = wx + 512;
    const float bv = bias_l[rho * 16 + lm];                   // bias keyed by D col = gate-row
    const __hip_bfloat16* hbA = hbuf + (size_t)tokA * H_ + quad * 8;

    // ---- epilogue mapping: thread (tid<256) owns (token b_loc, column jj) ----
    const int b_loc = (tid >> 3) & 31, jj = tid & 7;
    const int b_glob = grp * TOK + b_loc;
    const int* inpp = inp + (size_t)b_glob * S_;
    float* outp = out + (size_t)b_glob * S_ * H_ + j0 + jj;
    __hip_bfloat16* hwp = hbuf + (size_t)b_glob * H_ + j0 + jj;
    float creg = 0.0f, hlast = 0.0f;

    // ---- distributed barrier: one 64B-padded flag per wg; wave0 polls all 64 ----
    unsigned int* myflag = bar + (grp * WPG + r) * FSTR;
    volatile const unsigned int* pollp = bar + (grp * WPG + lane) * FSTR;

    // ---- prologue: acc_next = bias + Xproj(t=0); prefetch cell(0) ----
    f32x4 acc_next;
    {
        f32x4 ax = {bv, bv, bv, bv};
        const float* xp = xbase;
#pragma unroll
        for (int ks = 0; ks < 16; ++ks) {
            float4 f0 = *(const float4*)(xp + ks * 32);
            float4 f1 = *(const float4*)(xp + ks * 32 + 4);
            bf16x8 a = cvt8(f0, f1);
            bf16x8 b = *(const bf16x8*)(wx + ks * 32);
            ax = __builtin_amdgcn_mfma_f32_16x16x32_bf16(a, b, ax, 0, 0, 0);
        }
        acc_next = ax;
    }
    int cell_next = inpp[0];

    for (int t = 0; t < S_; ++t) {
        f32x4 acc = acc_next;
        const int cell_cur = cell_next;

        // h-projection, K = H = 512 (bf16 ping-pong; h_0 = 0 -> skip at t=0)
        if (t > 0) {
            const __hip_bfloat16* hp = hbA + (size_t)(t & 1) * B_ * H_;
#pragma unroll
            for (int ks = 0; ks < 16; ++ks) {
                bf16x8 a = *(const bf16x8*)(hp + ks * 32);
                bf16x8 b = *(const bf16x8*)(wh + ks * 32);
                acc = __builtin_amdgcn_mfma_f32_16x16x32_bf16(a, b, acc, 0, 0, 0);
            }
        }

        // D[m][n]: token row = mtile*16 + quad*4 + reg, gate col = rho*16 + lm
        {
            float* gp = gbuf + (mtile * 16 + quad * 4) * GSTR + rho * 16 + lm;
            gp[0] = acc[0]; gp[GSTR] = acc[1]; gp[2 * GSTR] = acc[2]; gp[3 * GSTR] = acc[3];
        }
        __syncthreads();

        if (tid < 256) {
            int cell = cell_cur & 1;                     // vocab id % 2
            const float* gb = gbuf + b_loc * GSTR + cell * 32 + jj;
            float iv = gb[0], fv = gb[8], gv = gb[16], ov = gb[24];
            creg  = sigf(fv) * creg + sigf(iv) * tanhf(gv);
            hlast = sigf(ov) * tanhf(creg);
            hwp[(size_t)((t + 1) & 1) * B_ * H_] = __float2bfloat16(hlast);  // bf16 for next step
        }

        // drain all waves' hbuf stores (syncthreads implies vmcnt(0)), then release OWN flag
        // (plain store to a private line — no RMW serialization across 64 wgs)
        __syncthreads();
        if (tid == 0)
            __hip_atomic_store(myflag, (unsigned int)(t + 1),
                               __ATOMIC_RELEASE, __HIP_MEMORY_SCOPE_AGENT);

        // ---- shadow region: independent of other wgs, hidden under the barrier wait ----
        if (tid < 256) outp[(size_t)t * H_] = hlast;     // f32 output, nobody reads it
        {
            int tn = (t + 1 < S_) ? (t + 1) : (S_ - 1);
            cell_next = inpp[tn];                        // prefetch next routing id
        }
        {
            f32x4 ax = {bv, bv, bv, bv};
            if (t + 1 < S_) {
                const float* xp = xbase + (size_t)(t + 1) * E_;
#pragma unroll
                for (int ks = 0; ks < 16; ++ks) {
                    float4 f0 = *(const float4*)(xp + ks * 32);
                    float4 f1 = *(const float4*)(xp + ks * 32 + 4);
                    bf16x8 a = cvt8(f0, f1);
                    bf16x8 b = *(const bf16x8*)(wx + ks * 32);
                    ax = __builtin_amdgcn_mfma_f32_16x16x32_bf16(a, b, ax, 0, 0, 0);
                }
            }
            acc_next = ax;
        }

        // ---- detection: wave0's 64 lanes load all 64 flags in one instruction ----
        if (wid == 0) {
            const unsigned int tgt = (unsigned int)(t + 1);
            unsigned int guard = 0;
            while (!__all((int)(*pollp >= tgt))) {
                __builtin_amdgcn_s_sleep(1);
                if (++guard > 0x08000000u) break;   // ~5s tripwire: wrong answer beats dead container
            }
            __builtin_amdgcn_fence(__ATOMIC_ACQUIRE, "agent");
        }
        __syncthreads();
    }

    if (tid < 256) {
        size_t base = (size_t)B_ * S_ * H_;
        out[base + (size_t)b_glob * H_ + j0 + jj] = hlast;                    // h_last
        out[base + (size_t)B_ * H_ + (size_t)b_glob * H_ + j0 + jj] = creg;   // c_last
    }
}

extern "C" void kernel_launch(void* const* d_in, const int* in_sizes, int n_in,
                              void* d_out, int out_size, void* d_ws, size_t ws_size,
                              hipStream_t stream) {
    const int* inp     = (const int*)d_in[0];
    const float* embed = (const float*)d_in[1];
    const float* Wih   = (const float*)d_in[2];
    const float* Whh   = (const float*)d_in[3];
    const float* bih   = (const float*)d_in[4];
    const float* bhh   = (const float*)d_in[5];
    float* out         = (float*)d_out;

    unsigned int* bar    = (unsigned int*)d_ws;                        // 16 KB flag region
    __hip_bfloat16* hbuf = (__hip_bfloat16*)((char*)d_ws + 16384);     // 2 x B x H bf16 = 256 KB

    static_assert(SMEM_BYTES <= 160 * 1024, "LDS overflow");
    hipFuncSetAttribute((const void*)lstm_kernel,
                        hipFuncAttributeMaxDynamicSharedMemorySize, SMEM_BYTES);

    hipLaunchKernelGGL(init_ws_kernel, dim3(1), dim3(256), 0, stream, bar);
    hipLaunchKernelGGL(lstm_kernel, dim3(256), dim3(512), SMEM_BYTES, stream,
                       inp, embed, Wih, Whh, bih, bhh, out, bar, hbuf);
}

// Round 5
// 16774.928 us; speedup vs baseline: 1.1076x; 1.1076x over previous
//
#include <hip/hip_runtime.h>
#include <hip/hip_bf16.h>

typedef __bf16 bf16x8 __attribute__((ext_vector_type(8)));
typedef float f32x4 __attribute__((ext_vector_type(4)));
typedef unsigned long long u64;

#define B_ 128
#define S_ 1024
#define E_ 512
#define H_ 512
#define TOK 32            // tokens (sequences) per group
#define KROWS 64          // gate-rows per wg: 2 cells x 4 gates x 8 columns
#define WSTRIDE 1032      // 1024 + 8 bf16 pad (row stride 516 dwords == 4 mod 32)
#define GSTR 65           // gbuf row stride (f32)
#define NGRP 4
#define WPG 64            // workgroups per group
#define FSTR 16           // flag stride in dwords (64B padding)
#define SMEM_BYTES (KROWS * WSTRIDE * 2 + 64 * 4 + TOK * GSTR * 4)  // 140672

__device__ __forceinline__ float sigf(float x) { return 1.0f / (1.0f + __expf(-x)); }

__device__ __forceinline__ bf16x8 cvt8(float4 a, float4 b) {
    bf16x8 r;
    r[0] = (__bf16)a.x; r[1] = (__bf16)a.y; r[2] = (__bf16)a.z; r[3] = (__bf16)a.w;
    r[4] = (__bf16)b.x; r[5] = (__bf16)b.y; r[6] = (__bf16)b.z; r[7] = (__bf16)b.w;
    return r;
}

union bfpack { u64 q[2]; bf16x8 v; };
union bfbits { __hip_bfloat16 b; unsigned short s; };

__global__ void init_ws_kernel(unsigned int* bar) {
    // zero the whole flag region: NGRP * WPG * FSTR dwords = 16 KB
    for (int i = threadIdx.x; i < NGRP * WPG * FSTR; i += 256) bar[i] = 0u;
}

__global__ void __launch_bounds__(512, 2)
lstm_kernel(const int* __restrict__ inp, const float* __restrict__ embed,
            const float* __restrict__ Wih, const float* __restrict__ Whh,
            const float* __restrict__ bih, const float* __restrict__ bhh,
            float* __restrict__ out, unsigned int* __restrict__ bar,
            __hip_bfloat16* __restrict__ hbuf)
{
    extern __shared__ char smem[];
    __hip_bfloat16* wbuf = (__hip_bfloat16*)smem;                 // [KROWS][WSTRIDE], [0,512)=W_ih row, [512,1024)=W_hh row
    float* bias_l = (float*)(smem + KROWS * WSTRIDE * 2);         // [64]
    float* gbuf   = bias_l + 64;                                  // [TOK][GSTR]

    const int tid = threadIdx.x;
    const int bid = blockIdx.x;
    const int grp = bid & 3;       // group: 64 wgs on XCDs {grp, grp+4}
    const int r   = bid >> 2;      // 0..63 column-block
    const int j0  = r * 8;

    // ---- stage weights (f32 -> bf16) into LDS, once. row n = cell*32 + gate*8 + jj ----
    for (int it = tid; it < KROWS * 256; it += 512) {
        int n = it >> 8;
        int q = it & 255;          // float4 index: 0..127 -> W_ih, 128..255 -> W_hh
        int cell = n >> 5, rem = n & 31, gate = rem >> 3, jj = rem & 7;
        size_t grow = (size_t)(cell * 2048 + gate * 512 + j0 + jj);
        float4 v;
        int dstoff;
        if (q < 128) { v = ((const float4*)(Wih + grow * E_))[q];       dstoff = q * 4; }
        else         { v = ((const float4*)(Whh + grow * H_))[q - 128]; dstoff = 512 + (q - 128) * 4; }
        __hip_bfloat16* dst = wbuf + n * WSTRIDE + dstoff;
        dst[0] = __float2bfloat16(v.x); dst[1] = __float2bfloat16(v.y);
        dst[2] = __float2bfloat16(v.z); dst[3] = __float2bfloat16(v.w);
    }
    if (tid < 64) {
        int n = tid, cell = n >> 5, rem = n & 31, gate = rem >> 3, jj = rem & 7;
        size_t off = (size_t)cell * 2048 + gate * 512 + j0 + jj;
        bias_l[tid] = bih[off] + bhh[off];
    }
    __syncthreads();

    // ---- MFMA task mapping: 8 waves = 2 token-tiles x 4 row-tiles ----
    const int lane = tid & 63, wid = tid >> 6;
    const int lm = lane & 15, quad = lane >> 4;
    const int mtile = wid & 1, rho = wid >> 1;
    const int tokA = grp * TOK + mtile * 16 + lm;             // A-operand token (m = lm)
    const float* xbase = embed + (size_t)tokA * S_ * E_ + quad * 8;
    const __hip_bfloat16* wx = wbuf + (rho * 16 + lm) * WSTRIDE + quad * 8;
    const __hip_bfloat16* wh = wx + 512;
    const float bv = bias_l[rho * 16 + lm];                   // bias keyed by D col = gate-row
    const __hip_bfloat16* hbA = hbuf + (size_t)tokA * H_ + quad * 8;

    // ---- epilogue mapping: thread (tid<256) owns (token b_loc, column jj) ----
    const int b_loc = (tid >> 3) & 31, jj = tid & 7;
    const int b_glob = grp * TOK + b_loc;
    const int* inpp = inp + (size_t)b_glob * S_;
    float* outp = out + (size_t)b_glob * S_ * H_ + j0 + jj;
    __hip_bfloat16* hwp = hbuf + (size_t)b_glob * H_ + j0 + jj;
    float creg = 0.0f, hlast = 0.0f;

    // ---- distributed barrier: one 64B-padded flag per wg; wave0 polls all 64 ----
    // ALL cross-wg traffic (h, flags) is volatile = HW cache-bypass (write-through /
    // read-through at the coherence point). NO fences, NO wbl2/inv in the loop.
    volatile unsigned int* myflag = bar + (grp * WPG + r) * FSTR;
    volatile const unsigned int* pollp = bar + (grp * WPG + lane) * FSTR;

    // ---- prologue: acc_next = bias + Xproj(t=0); prefetch cell(0) ----
    f32x4 acc_next;
    {
        f32x4 ax = {bv, bv, bv, bv};
        const float* xp = xbase;
#pragma unroll
        for (int ks = 0; ks < 16; ++ks) {
            float4 f0 = *(const float4*)(xp + ks * 32);
            float4 f1 = *(const float4*)(xp + ks * 32 + 4);
            bf16x8 a = cvt8(f0, f1);
            bf16x8 b = *(const bf16x8*)(wx + ks * 32);
            ax = __builtin_amdgcn_mfma_f32_16x16x32_bf16(a, b, ax, 0, 0, 0);
        }
        acc_next = ax;
    }
    int cell_next = inpp[0];

    for (int t = 0; t < S_; ++t) {
        f32x4 acc = acc_next;
        const int cell_cur = cell_next;

        // h-projection, K = H = 512 (volatile bypass loads from coherence point;
        // h_0 = 0 -> skip at t=0)
        if (t > 0) {
            const volatile u64* hp = (const volatile u64*)(hbA + (size_t)(t & 1) * B_ * H_);
#pragma unroll
            for (int ks = 0; ks < 16; ++ks) {
                bfpack u;
                u.q[0] = hp[ks * 8];
                u.q[1] = hp[ks * 8 + 1];
                bf16x8 b = *(const bf16x8*)(wh + ks * 32);
                acc = __builtin_amdgcn_mfma_f32_16x16x32_bf16(u.v, b, acc, 0, 0, 0);
            }
        }

        // D[m][n]: token row = mtile*16 + quad*4 + reg, gate col = rho*16 + lm
        {
            float* gp = gbuf + (mtile * 16 + quad * 4) * GSTR + rho * 16 + lm;
            gp[0] = acc[0]; gp[GSTR] = acc[1]; gp[2 * GSTR] = acc[2]; gp[3 * GSTR] = acc[3];
        }
        __syncthreads();

        if (tid < 256) {
            int cell = cell_cur & 1;                     // vocab id % 2
            const float* gb = gbuf + b_loc * GSTR + cell * 32 + jj;
            float iv = gb[0], fv = gb[8], gv = gb[16], ov = gb[24];
            creg  = sigf(fv) * creg + sigf(iv) * tanhf(gv);
            hlast = sigf(ov) * tanhf(creg);
            // volatile write-through: immediately visible at coherence point, no dirty L2 line
            bfbits cv; cv.b = __float2bfloat16(hlast);
            *(volatile unsigned short*)(hwp + (size_t)((t + 1) & 1) * B_ * H_) = cv.s;
        }

        // syncthreads drains each wave's vmcnt(0): all h write-throughs acked
        // before tid0's flag store can issue -> flag never beats h to the IF
        __syncthreads();
        if (tid == 0) *myflag = (unsigned int)(t + 1);

        // ---- shadow region: independent of other wgs, hidden under the barrier wait ----
        if (tid < 256) outp[(size_t)t * H_] = hlast;     // f32 output, nobody reads it
        {
            int tn = (t + 1 < S_) ? (t + 1) : (S_ - 1);
            cell_next = inpp[tn];                        // prefetch next routing id
        }
        {
            f32x4 ax = {bv, bv, bv, bv};
            if (t + 1 < S_) {
                const float* xp = xbase + (size_t)(t + 1) * E_;
#pragma unroll
                for (int ks = 0; ks < 16; ++ks) {
                    float4 f0 = *(const float4*)(xp + ks * 32);
                    float4 f1 = *(const float4*)(xp + ks * 32 + 4);
                    bf16x8 a = cvt8(f0, f1);
                    bf16x8 b = *(const bf16x8*)(wx + ks * 32);
                    ax = __builtin_amdgcn_mfma_f32_16x16x32_bf16(a, b, ax, 0, 0, 0);
                }
            }
            acc_next = ax;
        }

        // ---- detection: wave0's 64 lanes bypass-load all 64 flags; no fence needed,
        //      h is read with bypass loads too ----
        if (wid == 0) {
            const unsigned int tgt = (unsigned int)(t + 1);
            unsigned int guard = 0;
            while (!__all((int)(*pollp >= tgt))) {
                __builtin_amdgcn_s_sleep(4);
                if (++guard > 0x02000000u) break;   // tripwire: wrong answer beats dead container
            }
        }
        __syncthreads();
    }

    if (tid < 256) {
        size_t base = (size_t)B_ * S_ * H_;
        out[base + (size_t)b_glob * H_ + j0 + jj] = hlast;                    // h_last
        out[base + (size_t)B_ * H_ + (size_t)b_glob * H_ + j0 + jj] = creg;   // c_last
    }
}

extern "C" void kernel_launch(void* const* d_in, const int* in_sizes, int n_in,
                              void* d_out, int out_size, void* d_ws, size_t ws_size,
                              hipStream_t stream) {
    const int* inp     = (const int*)d_in[0];
    const float* embed = (const float*)d_in[1];
    const float* Wih   = (const float*)d_in[2];
    const float* Whh   = (const float*)d_in[3];
    const float* bih   = (const float*)d_in[4];
    const float* bhh   = (const float*)d_in[5];
    float* out         = (float*)d_out;

    unsigned int* bar    = (unsigned int*)d_ws;                        // 16 KB flag region
    __hip_bfloat16* hbuf = (__hip_bfloat16*)((char*)d_ws + 16384);     // 2 x B x H bf16 = 256 KB

    static_assert(SMEM_BYTES <= 160 * 1024, "LDS overflow");
    hipFuncSetAttribute((const void*)lstm_kernel,
                        hipFuncAttributeMaxDynamicSharedMemorySize, SMEM_BYTES);

    hipLaunchKernelGGL(init_ws_kernel, dim3(1), dim3(256), 0, stream, bar);
    hipLaunchKernelGGL(lstm_kernel, dim3(256), dim3(512), SMEM_BYTES, stream,
                       inp, embed, Wih, Whh, bih, bhh, out, bar, hbuf);
}